// Round 1
// 826.496 us; speedup vs baseline: 1.2957x; 1.2957x over previous
//
#include <hip/hip_runtime.h>
#include <math.h>

#define B_   2
#define S_   2048
#define DIM_ 1024
#define H_   16
#define QD_  64
#define VD_  96
#define NQKV 1184  // H_*QD_ + QD_ + VD_
#define EPS_ 1e-8f

using half_t = _Float16;
using half8  = __attribute__((ext_vector_type(8))) _Float16;
using half4v = __attribute__((ext_vector_type(4))) _Float16;
using f32x4  = __attribute__((ext_vector_type(4))) float;

// ---------------------------------------------------------------------------
// RMSNorm: one block per row, 256 threads, float4 in, half4 out.
// ---------------------------------------------------------------------------
__global__ __launch_bounds__(256) void rmsnorm_h(const float* __restrict__ x,
                                                 const float* __restrict__ w,
                                                 half_t* __restrict__ xn) {
    int row = blockIdx.x;
    int t = threadIdx.x;
    float4 v = ((const float4*)(x + (size_t)row * DIM_))[t];
    float ss = v.x * v.x + v.y * v.y + v.z * v.z + v.w * v.w;
#pragma unroll
    for (int off = 32; off > 0; off >>= 1) ss += __shfl_down(ss, off, 64);
    __shared__ float wsum[4];
    if ((t & 63) == 0) wsum[t >> 6] = ss;
    __syncthreads();
    float tot = wsum[0] + wsum[1] + wsum[2] + wsum[3];
    float scale = rsqrtf(tot * (1.0f / DIM_) + EPS_);
    float4 wv = ((const float4*)w)[t];
    half4v o;
    o[0] = (half_t)(v.x * wv.x * scale);
    o[1] = (half_t)(v.y * wv.y * scale);
    o[2] = (half_t)(v.z * wv.z * scale);
    o[3] = (half_t)(v.w * wv.w * scale);
    ((half4v*)(xn + (size_t)row * DIM_))[t] = o;
}

// ---------------------------------------------------------------------------
// Tiled transpose + convert to fp16: out[C x R] = in[R x C]^T (ld-aware).
// blockIdx.z batches with independent in/out batch strides.
// ---------------------------------------------------------------------------
template <typename TIN>
__global__ __launch_bounds__(256) void transpose_cvt(const TIN* __restrict__ in,
                                                     half_t* __restrict__ out,
                                                     int R, int C, int ldin,
                                                     size_t zin, size_t zout) {
    __shared__ float tile[32][33];
    in += (size_t)blockIdx.z * zin;
    out += (size_t)blockIdx.z * zout;
    int tx = threadIdx.x & 31, ty = threadIdx.x >> 5;
#pragma unroll
    for (int i = 0; i < 32; i += 8) {
        int r = blockIdx.y * 32 + ty + i, c = blockIdx.x * 32 + tx;
        tile[ty + i][tx] = (float)in[(size_t)r * ldin + c];
    }
    __syncthreads();
#pragma unroll
    for (int i = 0; i < 32; i += 8) {
        int orow = blockIdx.x * 32 + ty + i, ocol = blockIdx.y * 32 + tx;
        out[(size_t)orow * R + ocol] = (half_t)tile[tx][ty + i];
    }
}

// ---------------------------------------------------------------------------
// Small helper: fused QKV bias vector (zeros for Q,K; bv for V region).
// ---------------------------------------------------------------------------
__global__ __launch_bounds__(256) void fill_qkv_bias(const float* __restrict__ bv,
                                                     float* __restrict__ bq) {
    int i = blockIdx.x * 256 + threadIdx.x;
    if (i < NQKV) bq[i] = (i >= H_ * QD_ + QD_) ? bv[i - (H_ * QD_ + QD_)] : 0.0f;
}

// ---------------------------------------------------------------------------
// fp16 MFMA GEMM: C[M x N] = A[M x K] @ BT[N x K]^T (+ bias). fp32 accum.
// 128x128 tile, BK=32, 4 waves in 2x2 of 64x64, 16x16x32_f16 MFMA.
// Register-prefetched staging: tile k+1 loads issue during tile k's MFMA.
// M mult of 128, K mult of 32; N guarded.
// ---------------------------------------------------------------------------
template <typename OutT, bool BIAS>
__global__ __launch_bounds__(256) void gemm_h(const half_t* __restrict__ A,
                                              const half_t* __restrict__ BT,
                                              OutT* __restrict__ C,
                                              const float* __restrict__ bias,
                                              int M, int N, int K) {
    __shared__ half_t As[128][40];
    __shared__ half_t Bs[128][40];
    int t = threadIdx.x;
    int w = t >> 6, lane = t & 63, l15 = lane & 15, l4 = lane >> 4;
    int wm = (w >> 1) * 64, wn = (w & 1) * 64;
    int m0 = blockIdx.y * 128, n0 = blockIdx.x * 128;
    int r0 = t >> 2, off0 = (t & 3) * 8;
    f32x4 acc[4][4] = {};
    const half8 hz = {};

    const half_t* Ap0 = A + (size_t)(m0 + r0) * K + off0;
    const half_t* Ap1 = Ap0 + (size_t)64 * K;
    const half_t* Bp0 = BT + (size_t)(n0 + r0) * K + off0;
    const half_t* Bp1 = Bp0 + (size_t)64 * K;
    bool bok0 = (n0 + r0) < N, bok1 = (n0 + r0 + 64) < N;

    half8 a0 = *(const half8*)Ap0;
    half8 a1 = *(const half8*)Ap1;
    half8 b0 = bok0 ? *(const half8*)Bp0 : hz;
    half8 b1 = bok1 ? *(const half8*)Bp1 : hz;

    for (int k0 = 0; k0 < K; k0 += 32) {
        __syncthreads();
        *(half8*)&As[r0][off0] = a0;
        *(half8*)&As[r0 + 64][off0] = a1;
        *(half8*)&Bs[r0][off0] = b0;
        *(half8*)&Bs[r0 + 64][off0] = b1;
        __syncthreads();
        if (k0 + 32 < K) {  // prefetch next k-tile; overlaps MFMA below
            a0 = *(const half8*)(Ap0 + k0 + 32);
            a1 = *(const half8*)(Ap1 + k0 + 32);
            b0 = bok0 ? *(const half8*)(Bp0 + k0 + 32) : hz;
            b1 = bok1 ? *(const half8*)(Bp1 + k0 + 32) : hz;
        }
        half8 af[4], bf[4];
#pragma unroll
        for (int mt = 0; mt < 4; ++mt) af[mt] = *(const half8*)&As[wm + mt * 16 + l15][l4 * 8];
#pragma unroll
        for (int nt = 0; nt < 4; ++nt) bf[nt] = *(const half8*)&Bs[wn + nt * 16 + l15][l4 * 8];
#pragma unroll
        for (int mt = 0; mt < 4; ++mt)
#pragma unroll
            for (int nt = 0; nt < 4; ++nt)
                acc[mt][nt] =
                    __builtin_amdgcn_mfma_f32_16x16x32_f16(af[mt], bf[nt], acc[mt][nt], 0, 0, 0);
    }

#pragma unroll
    for (int mt = 0; mt < 4; ++mt)
#pragma unroll
        for (int nt = 0; nt < 4; ++nt) {
            int n = n0 + wn + nt * 16 + l15;
            if (n < N) {
#pragma unroll
                for (int reg = 0; reg < 4; ++reg) {
                    int m = m0 + wm + mt * 16 + l4 * 4 + reg;
                    float v = acc[mt][nt][reg];
                    if (BIAS) v += bias[n];
                    C[(size_t)m * N + n] = (OutT)v;
                }
            }
        }
}

// ---------------------------------------------------------------------------
// RoPE (fp16 in/out, fp32 math). One thread per (chunk, pair i<32).
// ---------------------------------------------------------------------------
__global__ __launch_bounds__(256) void rope_h(const half_t* __restrict__ in, int ldin,
                                              half_t* __restrict__ out,
                                              int hc, int total_pairs) {
    int p = blockIdx.x * 256 + threadIdx.x;
    if (p >= total_pairs) return;
    int i = p & 31;
    int chunk = p >> 5;
    int row = chunk / hc;
    int h = chunk - row * hc;
    int s = row & (S_ - 1);
    const half_t* src = in + (size_t)row * ldin + h * 64 + 2 * i;
    float x1 = (float)src[0], x2 = (float)src[1];
    float freq = exp2f((float)i * (-11.0f / 31.0f));
    float th = (float)s * freq;
    float sn, cs;
    sincosf(th, &sn, &cs);
    half_t* dst = out + (size_t)chunk * 64;
    dst[i] = (half_t)(x1 * cs - x2 * sn);
    dst[i + 32] = (half_t)(x1 * sn + x2 * cs);
}

// ---------------------------------------------------------------------------
// Attention (MFMA), software-pipelined. Block = 64 q-rows of one (b,h),
// 4 waves x 16 rows, j-loop step 64.
// Pipeline: at the top of tile j's compute, issue {K/V tile j+1 -> regs,
// bias tile j+1 -> regs}; consume bias tile j from regs; ds_write the
// prefetched K/V after the tail barrier. HBM latency hides under QK/exp/PV.
// Softcap bounds logits to [-5,5] -> no running max needed.
// LDS: ks 9.2KB + vs 13.8KB + ps 17.4KB = 40.4KB -> 4 blocks/CU.
// ---------------------------------------------------------------------------
__global__ __launch_bounds__(256, 4) void attn_mfma(const half_t* __restrict__ qh,  // (B,S,H,64)
                                                    const half_t* __restrict__ kh,  // (B,S,64)
                                                    const half_t* __restrict__ vt,  // (B,96,S)
                                                    const float* __restrict__ bias, // (B,H,S,S)
                                                    half_t* __restrict__ ctx) {     // (B,S,H*96)
    __shared__ half_t ks[64][72];
    __shared__ half_t vs[96][72];
    __shared__ float ps[4][16][68];

    int t = threadIdx.x;
    int w = t >> 6, lane = t & 63, l15 = lane & 15, l4 = lane >> 4;
    int i0 = blockIdx.x * 64, h = blockIdx.y, b = blockIdx.z;

    // Q A-fragments (K=64 -> two K=32 frags), held in registers for all j.
    const half_t* qbase =
        qh + (((size_t)(b * S_ + i0 + w * 16 + l15) * H_ + h) << 6) + l4 * 8;
    half8 qf0 = *(const half8*)qbase;
    half8 qf1 = *(const half8*)(qbase + 32);

    f32x4 cacc[6] = {};
    float rsum[4] = {0.f, 0.f, 0.f, 0.f};

    int sr = t >> 3, so = (t & 7) * 8;  // staging: row, halfs-offset (16B chunks)
    const float* bbase =
        bias + ((size_t)(b * H_ + h) * S_ + i0 + w * 16 + l4 * 4) * S_ + l15;
    const half_t* krow0 = kh + (((size_t)b * S_ + sr) << 6) + so;  // + (j0<<6)
    const half_t* krow1 = krow0 + ((size_t)32 << 6);
    const half_t* vrow0 = vt + ((size_t)b * 96 + sr) * S_ + so;    // + j0
    const half_t* vrow1 = vrow0 + (size_t)32 * S_;
    const half_t* vrow2 = vrow0 + (size_t)64 * S_;

    half8 kr0, kr1, vr0, vr1, vr2;
    float bc[16], bn[16];

    // ---- prologue: tile j0 = 0 ----
    kr0 = *(const half8*)krow0;
    kr1 = *(const half8*)krow1;
    vr0 = *(const half8*)vrow0;
    vr1 = *(const half8*)vrow1;
    vr2 = *(const half8*)vrow2;
#pragma unroll
    for (int nt = 0; nt < 4; ++nt)
#pragma unroll
        for (int reg = 0; reg < 4; ++reg)
            bc[nt * 4 + reg] = bbase[nt * 16 + (size_t)reg * S_];

    *(half8*)&ks[sr][so] = kr0;
    *(half8*)&ks[sr + 32][so] = kr1;
    *(half8*)&vs[sr][so] = vr0;
    *(half8*)&vs[sr + 32][so] = vr1;
    *(half8*)&vs[sr + 64][so] = vr2;
    __syncthreads();

    for (int j0 = 0; j0 < S_; j0 += 64) {
        int jn = j0 + 64;
        bool more = jn < S_;

        // issue next-tile loads first: K/V (consumed at ds_write below),
        // then bias (consumed one tile later) -> counted vmcnt waits.
        if (more) {
            kr0 = *(const half8*)(krow0 + ((size_t)jn << 6));
            kr1 = *(const half8*)(krow1 + ((size_t)jn << 6));
            vr0 = *(const half8*)(vrow0 + jn);
            vr1 = *(const half8*)(vrow1 + jn);
            vr2 = *(const half8*)(vrow2 + jn);
#pragma unroll
            for (int nt = 0; nt < 4; ++nt)
#pragma unroll
                for (int reg = 0; reg < 4; ++reg)
                    bn[nt * 4 + reg] = bbase[jn + nt * 16 + (size_t)reg * S_];
        }

        // QK^T + bias + softcap + exp; P (fp32) into per-wave LDS.
#pragma unroll
        for (int nt = 0; nt < 4; ++nt) {
            f32x4 s = {};
            half8 kb0 = *(const half8*)&ks[nt * 16 + l15][l4 * 8];
            half8 kb1 = *(const half8*)&ks[nt * 16 + l15][32 + l4 * 8];
            __builtin_amdgcn_s_setprio(1);
            s = __builtin_amdgcn_mfma_f32_16x16x32_f16(qf0, kb0, s, 0, 0, 0);
            s = __builtin_amdgcn_mfma_f32_16x16x32_f16(qf1, kb1, s, 0, 0, 0);
            __builtin_amdgcn_s_setprio(0);
#pragma unroll
            for (int reg = 0; reg < 4; ++reg) {
                float l = s[reg] + bc[nt * 4 + reg];
                float e2 = __expf(0.4f * l);                                // e^(2l/5)
                float tnh = 1.0f - 2.0f * __builtin_amdgcn_rcpf(e2 + 1.0f); // tanh(l/5)
                float p = __expf(5.0f * tnh);
                rsum[reg] += p;
                ps[w][l4 * 4 + reg][nt * 16 + l15] = p;
            }
        }
        // per-wave only: no __syncthreads needed (compiler orders DS ops).

        // PV: A-frags from ps (cvt fp32->fp16), B-frags from vs.
        half8 af[2];
#pragma unroll
        for (int kf = 0; kf < 2; ++kf) {
            f32x4 p0 = *(const f32x4*)&ps[w][l15][kf * 32 + l4 * 8];
            f32x4 p1 = *(const f32x4*)&ps[w][l15][kf * 32 + l4 * 8 + 4];
            half8 a;
#pragma unroll
            for (int e = 0; e < 4; ++e) {
                a[e] = (half_t)p0[e];
                a[e + 4] = (half_t)p1[e];
            }
            af[kf] = a;
        }
        __builtin_amdgcn_s_setprio(1);
#pragma unroll
        for (int nt = 0; nt < 6; ++nt) {
            half8 v0 = *(const half8*)&vs[nt * 16 + l15][l4 * 8];
            half8 v1 = *(const half8*)&vs[nt * 16 + l15][32 + l4 * 8];
            cacc[nt] = __builtin_amdgcn_mfma_f32_16x16x32_f16(af[0], v0, cacc[nt], 0, 0, 0);
            cacc[nt] = __builtin_amdgcn_mfma_f32_16x16x32_f16(af[1], v1, cacc[nt], 0, 0, 0);
        }
        __builtin_amdgcn_s_setprio(0);

        if (more) {  // uniform branch: syncthreads legal
            __syncthreads();
            *(half8*)&ks[sr][so] = kr0;
            *(half8*)&ks[sr + 32][so] = kr1;
            *(half8*)&vs[sr][so] = vr0;
            *(half8*)&vs[sr + 32][so] = vr1;
            *(half8*)&vs[sr + 64][so] = vr2;
            __syncthreads();
#pragma unroll
            for (int q = 0; q < 16; ++q) bc[q] = bn[q];
        }
    }

    // rowsum: reduce across the 16 lanes sharing l4 (same 4 rows).
#pragma unroll
    for (int m = 1; m < 16; m <<= 1)
#pragma unroll
        for (int reg = 0; reg < 4; ++reg) rsum[reg] += __shfl_xor(rsum[reg], m, 64);
    float rinv[4];
#pragma unroll
    for (int reg = 0; reg < 4; ++reg) rinv[reg] = __builtin_amdgcn_rcpf(rsum[reg]);

#pragma unroll
    for (int nt = 0; nt < 6; ++nt)
#pragma unroll
        for (int reg = 0; reg < 4; ++reg) {
            int i = i0 + w * 16 + l4 * 4 + reg;
            ctx[((size_t)(b * S_ + i) * H_ + h) * VD_ + nt * 16 + l15] =
                (half_t)(cacc[nt][reg] * rinv[reg]);
        }
}

// ---------------------------------------------------------------------------
extern "C" void kernel_launch(void* const* d_in, const int* in_sizes, int n_in,
                              void* d_out, int out_size, void* d_ws, size_t ws_size,
                              hipStream_t stream) {
    (void)in_sizes; (void)n_in; (void)out_size; (void)ws_size;
    const float* x  = (const float*)d_in[0];
    const float* ab = (const float*)d_in[1];
    const float* rw = (const float*)d_in[2];
    const float* Wq = (const float*)d_in[3];
    const float* Wk = (const float*)d_in[4];
    const float* Wv = (const float*)d_in[5];
    const float* bv = (const float*)d_in[6];
    const float* Wo = (const float*)d_in[7];
    const float* bo = (const float*)d_in[8];
    float* out = (float*)d_out;

    const size_t R = (size_t)B_ * S_;  // 4096
    half_t* p = (half_t*)d_ws;
    half_t* xn_h  = p;  p += R * DIM_;
    half_t* qkv_h = p;  p += R * NQKV;          // fused (Q|K|V) pre-RoPE, ld=1184
    half_t* q_h   = p;  p += R * DIM_;          // (B,S,H,64) post-RoPE
    half_t* k_h   = p;  p += R * QD_;           // (B,S,64)  post-RoPE
    half_t* vtb   = p;  p += R * VD_;           // (B,96,S)
    half_t* ctx_h = p;  p += R * H_ * VD_;
    half_t* WqkvT = p;  p += (size_t)NQKV * DIM_;   // [1184][1024] = (Wq|Wk|Wv)^T
    half_t* WoT   = p;  p += (size_t)(H_ * VD_) * DIM_;
    float*  bqkv  = (float*)p;  p += 2 * NQKV;

    rmsnorm_h<<<dim3(R), 256, 0, stream>>>(x, rw, xn_h);

    // weight transposes (fp32 -> fp16, N x K layout); Wq/Wk/Wv land adjacent
    // in WqkvT forming the fused [1184][1024] B^T.
    half_t* WqT = WqkvT;
    half_t* WkT = WqkvT + (size_t)(H_ * QD_) * DIM_;
    half_t* WvT = WkT + (size_t)QD_ * DIM_;
    transpose_cvt<float><<<dim3(32, 32, 1), 256, 0, stream>>>(Wq, WqT, DIM_, H_ * QD_,
                                                              H_ * QD_, 0, 0);
    transpose_cvt<float><<<dim3(2, 32, 1), 256, 0, stream>>>(Wk, WkT, DIM_, QD_, QD_, 0, 0);
    transpose_cvt<float><<<dim3(3, 32, 1), 256, 0, stream>>>(Wv, WvT, DIM_, VD_, VD_, 0, 0);
    transpose_cvt<float><<<dim3(32, 48, 1), 256, 0, stream>>>(Wo, WoT, H_ * VD_, DIM_,
                                                              DIM_, 0, 0);
    fill_qkv_bias<<<dim3((NQKV + 255) / 256), 256, 0, stream>>>(bv, bqkv);

    // fused QKV projection: one well-parallelized GEMM (320 blocks) replaces
    // the N=1024/64/96 trio (the latter two ran on only 32 CUs).
    gemm_h<half_t, true><<<dim3(10, 32), 256, 0, stream>>>(xn_h, WqkvT, qkv_h, bqkv,
                                                           (int)R, NQKV, DIM_);

    // RoPE (reads from fused buffer, ld = NQKV)
    rope_h<<<dim3((R * H_ * 32) / 256), 256, 0, stream>>>(qkv_h, NQKV, q_h, H_,
                                                          (int)(R * H_ * 32));
    rope_h<<<dim3((R * 32) / 256), 256, 0, stream>>>(qkv_h + H_ * QD_, NQKV, k_h, 1,
                                                     (int)(R * 32));

    // V^T: fused buffer (B,S,96 @ ld 1184) -> (B,96,S)
    transpose_cvt<half_t><<<dim3(3, 64, 2), 256, 0, stream>>>(
        qkv_h + H_ * QD_ + QD_, vtb, S_, VD_, NQKV, (size_t)S_ * NQKV, (size_t)VD_ * S_);

    // attention
    attn_mfma<<<dim3(S_ / 64, H_, B_), 256, 0, stream>>>(q_h, k_h, vtb, ab, ctx_h);

    // output projection (fp32 out + bias)
    gemm_h<float, true><<<dim3(8, 32), 256, 0, stream>>>(ctx_h, WoT, out, bo,
                                                         (int)R, DIM_, H_ * VD_);
}